// Round 17
// baseline (61.616 us; speedup 1.0000x reference)
//
#include <hip/hip_runtime.h>
#include <cmath>
#include <complex>
#include <algorithm>

// ---------------- compile-time path metadata ----------------
#define NPATH 15
constexpr int PL1[NPATH] = {0,0,0, 1,1,1,1,1,1, 2,2,2,2,2,2};
constexpr int PL2[NPATH] = {0,1,2, 0,1,1,1,2,2, 0,1,1,2,2,2};
constexpr int PL3[NPATH] = {0,1,2, 1,0,1,2,1,2, 2,1,2,0,1,2};
constexpr int CGOFF[NPATH] = {0,1,10,35,44,53,80,125,170,245,270,315,390,415,490};
constexpr int CGTOT = 615;
constexpr int YOFF[3] = {0,1,4};

// Compacted per-half yc tables (flip layout: entry e, row n -> s_yg[e*16+n])
// half0 general {5,7,10,13}: bases {0,9,18,33}, raw-y base 48  (57 entries)
// half1 general {6,8,11,14}: bases {0,15,30,55}, raw-y base 80 (89 entries)
constexpr int YGMAX = 89;

struct CGArg { float v[CGTOT]; }; // alpha-folded real-basis CG

// ---------------- host: exact port of reference CG construction ----------------
static double factd(int n){ double r=1.0; for(int i=2;i<=n;++i) r*=(double)i; return r; }

static double su2_cg(int j1,int m1,int j2,int m2,int j3,int m3){
  if (m3 != m1+m2) return 0.0;
  double c = (double)(2*j3+1) * factd(j1+j2-j3) * factd(j1-j2+j3) * factd(-j1+j2+j3)
             / factd(j1+j2+j3+1);
  c = std::sqrt(c);
  c *= std::sqrt(factd(j3+m3)*factd(j3-m3)*factd(j1-m1)*factd(j1+m1)*factd(j2-m2)*factd(j2+m2));
  double s = 0.0;
  int kmin = std::max(0, std::max(j2-j3-m1, j1-j3+m2));
  int kmax = std::min(j1+j2-j3, std::min(j1-m1, j2+m2));
  for (int k=kmin;k<=kmax;++k){
    double d = factd(k)*factd(j1+j2-j3-k)*factd(j1-m1-k)*factd(j2+m2-k)
             * factd(j3-j2+m1+k)*factd(j3-j1-m2+k);
    s += ((k&1)? -1.0 : 1.0)/d;
  }
  return c*s;
}

static void qmat(int l, std::complex<double>* q){
  int d = 2*l+1;
  for (int a=0;a<d*d;++a) q[a] = std::complex<double>(0.0,0.0);
  const double r2 = 1.0/std::sqrt(2.0);
  for (int m=-l; m<0; ++m){
    q[(l+m)*d + (l-m)] = std::complex<double>(r2, 0.0);
    q[(l+m)*d + (l+m)] = std::complex<double>(0.0, -r2);
  }
  q[l*d + l] = std::complex<double>(1.0,0.0);
  for (int m=1; m<=l; ++m){
    double sg = (m&1)? -1.0 : 1.0;
    q[(l+m)*d + (l+m)] = std::complex<double>(sg*r2, 0.0);
    q[(l+m)*d + (l-m)] = std::complex<double>(0.0, sg*r2);
  }
  std::complex<double> ph = (l==0)? std::complex<double>(1,0)
                        : (l==1)? std::complex<double>(0,-1)
                                : std::complex<double>(-1,0);   // (-i)^l
  for (int a=0;a<d*d;++a) q[a] *= ph;
}

static void compute_cg(float* outv){
  const int npaths_to[3] = {3,6,6};
  for (int p=0;p<NPATH;++p){
    int l1=PL1[p], l2=PL2[p], l3=PL3[p];
    int d1=2*l1+1, d2=2*l2+1, d3=2*l3+1;
    std::complex<double> C[5][5][5];
    for (int a=0;a<5;++a) for(int b=0;b<5;++b) for(int c=0;c<5;++c) C[a][b][c]=std::complex<double>(0,0);
    for (int m1=-l1;m1<=l1;++m1) for (int m2=-l2;m2<=l2;++m2){
      int m3=m1+m2;
      if (std::abs(m3)<=l3) C[l1+m1][l2+m2][l3+m3] = su2_cg(l1,m1,l2,m2,l3,m3);
    }
    std::complex<double> U1[25],U2[25],U3[25];
    qmat(l1,U1); qmat(l2,U2); qmat(l3,U3);
    double Cr[5][5][5]; double nrm=0.0;
    for (int a=0;a<d1;++a) for (int b=0;b<d2;++b) for (int c=0;c<d3;++c){
      std::complex<double> s(0,0);
      for (int i=0;i<d1;++i) for (int j=0;j<d2;++j) for (int k=0;k<d3;++k)
        s += U1[i*d1+a]*U2[j*d2+b]*std::conj(U3[k*d3+c])*C[i][j][k];
      Cr[a][b][c] = s.real();
      nrm += s.real()*s.real();
    }
    nrm = std::sqrt(nrm);
    double alpha = 1.0/std::sqrt(64.0*(double)npaths_to[l3]);
    float* o = outv + CGOFF[p];
    int idx=0;
    for (int a=0;a<d1;++a) for (int b=0;b<d2;++b) for (int c=0;c<d3;++c)
      o[idx++] = (float)(Cr[a][b][c]/nrm*alpha);
  }
}

// ---------------- device ----------------
typedef short bf16x8 __attribute__((ext_vector_type(8)));
typedef float f32x4 __attribute__((ext_vector_type(4)));

#define MFMA16(A,B,C) __builtin_amdgcn_mfma_f32_16x16x32_bf16((A),(B),(C),0,0,0)

__device__ __forceinline__ unsigned cvtpk_bf16(float a, float b){
  unsigned r;
  asm("v_cvt_pk_bf16_f32 %0, %1, %2" : "=v"(r) : "v"(a), "v"(b));
  return r;
}

// x-fragment: lane (cl,q) holds x[row=cl][u=kt*32+q*8 ..+7]; XOR-swizzled 16B chunks (R2-verified)
__device__ __forceinline__ bf16x8 afrag(const unsigned short* s_xt, int plane, int kt, int row, int q){
  int c = (kt*4 + q) ^ (row & 7);
  return *reinterpret_cast<const bf16x8*>(s_xt + (plane*16 + row)*64 + c*8);
}
// W-fragment: lane (cl,q) holds W^T[w=wt*16+cl][u=kt*32+q*8..+7]
__device__ __forceinline__ bf16x8 wfrag(const unsigned short* WT, int p, int wt, int cl, int kt, int q){
  return *reinterpret_cast<const bf16x8*>(WT + p*4096 + (wt*16+cl)*64 + kt*32 + q*8);
}
__device__ __forceinline__ void xt_write_pk(unsigned short* s_xt, int plane, int n, int t16, uint2 pk){
  const int swz = (((t16>>1)^(n&7))<<3) + ((t16&1)<<2);
  *reinterpret_cast<uint2*>(s_xt + (plane*16 + n)*64 + swz) = pk;
}

__device__ __forceinline__ void pack_x(const float4& r0, const float4* r1, const float4* r2, uint2* xpk){
  const float* f0 = reinterpret_cast<const float*>(&r0);
  const float* f1 = reinterpret_cast<const float*>(r1);
  const float* f2 = reinterpret_cast<const float*>(r2);
  xpk[0].x = cvtpk_bf16(f0[0], f0[1]);  xpk[0].y = cvtpk_bf16(f0[2], f0[3]);
  #pragma unroll
  for (int i=0;i<3;++i){
    xpk[1+i].x = cvtpk_bf16(f1[0*3+i], f1[1*3+i]);
    xpk[1+i].y = cvtpk_bf16(f1[2*3+i], f1[3*3+i]);
  }
  #pragma unroll
  for (int i=0;i<5;++i){
    xpk[4+i].x = cvtpk_bf16(f2[0*5+i], f2[1*5+i]);
    xpk[4+i].y = cvtpk_bf16(f2[2*5+i], f2[3*5+i]);
  }
}

// stage this block's tile (x + compacted yc) — R13-verified
template<int HALF>
__device__ __forceinline__ void stage_tile(const float* __restrict__ x, const float* __restrict__ y,
                                           int nbase, unsigned short* s_xt, float* s_yg,
                                           const CGArg& cga, int tid, int n_s, int t16){
  const float* xb = x + (size_t)(nbase + n_s)*576;
  float4 r0 = *reinterpret_cast<const float4*>(xb + t16*4);
  float4 r1[3], r2[5];
  #pragma unroll
  for (int i=0;i<3;++i) r1[i] = *reinterpret_cast<const float4*>(xb + 64 + t16*12 + 4*i);
  #pragma unroll
  for (int i=0;i<5;++i) r2[i] = *reinterpret_cast<const float4*>(xb + 256 + t16*20 + 4*i);

  float yl[9];
  {
    const float* yrow = y + (size_t)(nbase + t16)*9;
    #pragma unroll
    for (int j=0;j<9;++j) yl[j] = yrow[j];
  }

  uint2 xpk[9];
  pack_x(r0, r1, r2, xpk);
  #pragma unroll
  for (int pl=0; pl<9; ++pl) xt_write_pk(s_xt, pl, n_s, t16, xpk[pl]);

  constexpr int RB = (HALF==0)? 48 : 80;
  if (tid < 16){
    #pragma unroll
    for (int j=0;j<9;++j) s_yg[(RB+j)*16 + tid] = yl[j];
  }

  if constexpr (HALF==0){
    constexpr int GPp[4] = {5,7,10,13};
    constexpr int NB[4]  = {0,9,18,33};
    #pragma unroll
    for (int u=0; u<4; ++u){
      const int p = GPp[u];
      const int d2=2*PL2[p]+1, d3=2*PL3[p]+1;
      const int cnt = (2*PL1[p]+1)*d3*16;
      for (int idx=tid; idx<cnt; idx+=256){
        int ik = idx >> 4;
        int i  = ik/d3;
        int k  = ik - i*d3;
        float s=0.f;
        for (int j=0;j<d2;++j)
          s += yl[YOFF[PL2[p]]+j]*cga.v[CGOFF[p]+(i*d2+j)*d3+k];
        s_yg[(NB[u]+ik)*16 + t16] = s;
      }
    }
  } else {
    constexpr int GPp[4] = {6,8,11,14};
    constexpr int NB[4]  = {0,15,30,55};
    #pragma unroll
    for (int u=0; u<4; ++u){
      const int p = GPp[u];
      const int d2=2*PL2[p]+1, d3=2*PL3[p]+1;
      const int cnt = (2*PL1[p]+1)*d3*16;
      for (int idx=tid; idx<cnt; idx+=256){
        int ik = idx >> 4;
        int i  = ik/d3;
        int k  = ik - i*d3;
        float s=0.f;
        for (int j=0;j<d2;++j)
          s += yl[YOFF[PL2[p]]+j]*cga.v[CGOFF[p]+(i*d2+j)*d3+k];
        s_yg[(NB[u]+ik)*16 + t16] = s;
      }
    }
  }
}

// ---- single-tile flipped path bodies, inline afrag (no register caches) ----
template<int PB,int D1,int D3,int E0,int AB>
__device__ __forceinline__ void gen1(const unsigned short* s_xt, bf16x8 b0, bf16x8 b1,
                                     const float* ygc, f32x4* acc, int cl, int q){
  const f32x4 z4 = {0.f,0.f,0.f,0.f};
  #pragma unroll
  for (int i=0;i<D1;++i){
    f32x4 T = MFMA16(b0, afrag(s_xt,PB+i,0,cl,q), z4);
    T       = MFMA16(b1, afrag(s_xt,PB+i,1,cl,q), T);
    #pragma unroll
    for (int k=0;k<D3;++k)
      acc[AB+k] += T*ygc[(E0+i*D3+k)*16];
  }
}
template<int PB,int D1,int AB>   // (l,0,l): acc[AB+i] += cy*T_i
__device__ __forceinline__ void dl0(const unsigned short* s_xt, bf16x8 b0, bf16x8 b1,
                                    float cy, f32x4* acc, int cl, int q){
  const f32x4 z4 = {0.f,0.f,0.f,0.f};
  #pragma unroll
  for (int i=0;i<D1;++i){
    f32x4 T = MFMA16(b0, afrag(s_xt,PB+i,0,cl,q), z4);
    T       = MFMA16(b1, afrag(s_xt,PB+i,1,cl,q), T);
    acc[AB+i] += T*cy;
  }
}
template<int D3,int YE,int AB>  // (0,l,l): plane-0; acc[AB+k] += c*y[YE+k]*T
__device__ __forceinline__ void d0l(const unsigned short* s_xt, bf16x8 b0, bf16x8 b1,
                                    float c, const float* ygc, f32x4* acc, int cl, int q){
  const f32x4 z4 = {0.f,0.f,0.f,0.f};
  f32x4 T = MFMA16(b0, afrag(s_xt,0,0,cl,q), z4);
  T       = MFMA16(b1, afrag(s_xt,0,1,cl,q), T);
  #pragma unroll
  for (int k=0;k<D3;++k)
    acc[AB+k] += T*(c*ygc[(YE+k)*16]);
}
template<int PB,int D1,int YE>  // (l,l,0): acc[0] += c * sum_i y[YE+i]*T_i
__device__ __forceinline__ void dll0(const unsigned short* s_xt, bf16x8 b0, bf16x8 b1,
                                     float c, const float* ygc, f32x4* acc, int cl, int q){
  const f32x4 z4 = {0.f,0.f,0.f,0.f};
  f32x4 s = z4;
  #pragma unroll
  for (int i=0;i<D1;++i){
    f32x4 T = MFMA16(b0, afrag(s_xt,PB+i,0,cl,q), z4);
    T       = MFMA16(b1, afrag(s_xt,PB+i,1,cl,q), T);
    s += T*ygc[(YE+i)*16];
  }
  acc[0] += s*c;
}

__global__ __launch_bounds__(256, 4)
void tp_kernel(const float* __restrict__ x, const float* __restrict__ y,
               const unsigned short* __restrict__ WT, float* __restrict__ out, CGArg cga)
{
  __shared__ __align__(16) unsigned short s_xt[9*16*64];  // 18432 B
  __shared__ __align__(16) float s_yg[YGMAX*16];          // 5696 B -> 24.1 KB total, 6 blocks/CU

  const int bid = blockIdx.x;
  // XCD-pairing: both halves of a tile share bid%8 -> same XCD L2
  const int tile = (bid & 7) | ((bid >> 4) << 3);
  const int half = (bid >> 3) & 1;
  const int n0 = tile * 16;

  const int tid = threadIdx.x;
  const int n_s = tid>>4, t16 = tid&15;

  if (half == 0) stage_tile<0>(x, y, n0, s_xt, s_yg, cga, tid, n_s, t16);
  else           stage_tile<1>(x, y, n0, s_xt, s_yg, cga, tid, n_s, t16);
  __syncthreads();

  const int lane = tid & 63, wt = tid >> 6;
  const int cl = lane & 15, q = lane >> 4;
  const float* ygc = s_yg + cl;          // per-lane scalar coefficients (b32 broadcast reads)
  const int wbase = wt*16 + q*4;

  const f32x4 z4 = {0.f,0.f,0.f,0.f};
  bf16x8 b0,b1,nb0,nb1;

  #define LDB(P) { nb0 = wfrag(WT,P,wt,cl,0,q); nb1 = wfrag(WT,P,wt,cl,1,q); }
  #define ADV    { b0 = nb0; b1 = nb1; }

  if (half == 0){
    constexpr int RB = 48;
    const float y0 = ygc[RB*16];
    f32x4 acc[4] = {z4,z4,z4,z4};
    b0 = wfrag(WT,0,wt,cl,0,q); b1 = wfrag(WT,0,wt,cl,1,q);

    LDB(1);  dl0<0,1,0>(s_xt, b0,b1, cga.v[CGOFF[0]]*y0, acc, cl,q);       ADV; // p0
    LDB(3);  d0l<3,RB+1,1>(s_xt, b0,b1, cga.v[CGOFF[1]], ygc, acc, cl,q);  ADV; // p1
    LDB(4);  dl0<1,3,1>(s_xt, b0,b1, cga.v[CGOFF[3]]*y0, acc, cl,q);       ADV; // p3
    LDB(5);  dll0<1,3,RB+1>(s_xt, b0,b1, cga.v[CGOFF[4]], ygc, acc, cl,q); ADV; // p4
    LDB(7);  gen1<1,3,3,0,1>(s_xt, b0,b1, ygc, acc, cl,q);                 ADV; // p5
    LDB(10); gen1<1,3,3,9,1>(s_xt, b0,b1, ygc, acc, cl,q);                 ADV; // p7
    LDB(12); gen1<4,5,3,18,1>(s_xt, b0,b1, ygc, acc, cl,q);                ADV; // p10
    LDB(13); dll0<4,5,RB+4>(s_xt, b0,b1, cga.v[CGOFF[12]], ygc, acc, cl,q);ADV; // p12
             gen1<4,5,3,33,1>(s_xt, b0,b1, ygc, acc, cl,q);                     // p13

    float* orow = out + (size_t)(n0 + cl)*576;
    *reinterpret_cast<float4*>(orow + wbase) =
        make_float4(acc[0][0],acc[0][1],acc[0][2],acc[0][3]);
    float4 v0 = make_float4(acc[1][0],acc[2][0],acc[3][0],acc[1][1]);
    float4 v1 = make_float4(acc[2][1],acc[3][1],acc[1][2],acc[2][2]);
    float4 v2 = make_float4(acc[3][2],acc[1][3],acc[2][3],acc[3][3]);
    float4* qp = reinterpret_cast<float4*>(orow + 64 + wbase*3);
    qp[0]=v0; qp[1]=v1; qp[2]=v2;
  } else {
    constexpr int RB = 80;
    const float y0 = ygc[RB*16];
    f32x4 acc[5] = {z4,z4,z4,z4,z4};
    b0 = wfrag(WT,2,wt,cl,0,q); b1 = wfrag(WT,2,wt,cl,1,q);

    LDB(6);  d0l<5,RB+4,0>(s_xt, b0,b1, cga.v[CGOFF[2]], ygc, acc, cl,q);  ADV; // p2
    LDB(8);  gen1<1,3,5,0,0>(s_xt, b0,b1, ygc, acc, cl,q);                 ADV; // p6
    LDB(9);  gen1<1,3,5,15,0>(s_xt, b0,b1, ygc, acc, cl,q);                ADV; // p8
    LDB(11); dl0<4,5,0>(s_xt, b0,b1, cga.v[CGOFF[9]]*y0, acc, cl,q);       ADV; // p9
    LDB(14); gen1<4,5,5,30,0>(s_xt, b0,b1, ygc, acc, cl,q);                ADV; // p11
             gen1<4,5,5,55,0>(s_xt, b0,b1, ygc, acc, cl,q);                     // p14

    float* orow = out + (size_t)(n0 + cl)*576;
    float4 v0 = make_float4(acc[0][0],acc[1][0],acc[2][0],acc[3][0]);
    float4 v1 = make_float4(acc[4][0],acc[0][1],acc[1][1],acc[2][1]);
    float4 v2 = make_float4(acc[3][1],acc[4][1],acc[0][2],acc[1][2]);
    float4 v3 = make_float4(acc[2][2],acc[3][2],acc[4][2],acc[0][3]);
    float4 v4 = make_float4(acc[1][3],acc[2][3],acc[3][3],acc[4][3]);
    float4* qp = reinterpret_cast<float4*>(orow + 256 + wbase*5);
    qp[0]=v0; qp[1]=v1; qp[2]=v2; qp[3]=v3; qp[4]=v4;
  }
  #undef LDB
  #undef ADV
}

// W[p][u][w] (fp32) -> WT[p][w][u] (bf16, RNE) once per launch
__global__ void wt_kernel(const float* __restrict__ W, unsigned short* __restrict__ WT){
  int t = blockIdx.x*256 + threadIdx.x;      // 61440 total
  int p = t >> 12, r = t & 4095, w = r >> 6, u = r & 63;
  float f = W[(p<<12) + (u<<6) + w];
  unsigned fu = __builtin_bit_cast(unsigned, f);
  unsigned rr = (fu + 0x7FFFu + ((fu>>16)&1u)) >> 16;
  WT[t] = (unsigned short)rr;
}

// ---------------- launch ----------------
extern "C" void kernel_launch(void* const* d_in, const int* in_sizes, int n_in,
                              void* d_out, int out_size, void* d_ws, size_t ws_size,
                              hipStream_t stream) {
  const float* x = (const float*)d_in[0];
  const float* y = (const float*)d_in[1];
  const float* W = (const float*)d_in[2];
  float* out = (float*)d_out;
  (void)in_sizes; (void)n_in; (void)out_size; (void)ws_size;

  unsigned short* WT = (unsigned short*)d_ws;   // 61440 * 2 B

  CGArg cga;
  compute_cg(cga.v);

  hipLaunchKernelGGL(wt_kernel, dim3(240), dim3(256), 0, stream, W, WT);
  hipLaunchKernelGGL(tp_kernel, dim3(4096), dim3(256), 0, stream, x, y, WT, out, cga);
}

// Round 18
// 55.124 us; speedup vs baseline: 1.1178x; 1.1178x over previous
//
#include <hip/hip_runtime.h>
#include <cmath>
#include <complex>
#include <algorithm>

// ---------------- compile-time path metadata ----------------
#define NPATH 15
constexpr int PL1[NPATH] = {0,0,0, 1,1,1,1,1,1, 2,2,2,2,2,2};
constexpr int PL2[NPATH] = {0,1,2, 0,1,1,1,2,2, 0,1,1,2,2,2};
constexpr int PL3[NPATH] = {0,1,2, 1,0,1,2,1,2, 2,1,2,0,1,2};
constexpr int CGOFF[NPATH] = {0,1,10,35,44,53,80,125,170,245,270,315,390,415,490};
constexpr int CGTOT = 615;
constexpr int YOFF[3] = {0,1,4};

// Compacted per-half yc entry tables (flip layout: entry e, row n -> s_yg[e*16+n])
// half0 general paths {5,7,10,13}: bases {0,9,18,33}, raw-y base 48, tot 57
// half1 general paths {6,8,11,14}: bases {0,15,30,55}, raw-y base 80, tot 89
constexpr int YGMAX = 89;

struct CGArg { float v[CGTOT]; }; // alpha-folded real-basis CG

// ---------------- host: exact port of reference CG construction ----------------
static double factd(int n){ double r=1.0; for(int i=2;i<=n;++i) r*=(double)i; return r; }

static double su2_cg(int j1,int m1,int j2,int m2,int j3,int m3){
  if (m3 != m1+m2) return 0.0;
  double c = (double)(2*j3+1) * factd(j1+j2-j3) * factd(j1-j2+j3) * factd(-j1+j2+j3)
             / factd(j1+j2+j3+1);
  c = std::sqrt(c);
  c *= std::sqrt(factd(j3+m3)*factd(j3-m3)*factd(j1-m1)*factd(j1+m1)*factd(j2-m2)*factd(j2+m2));
  double s = 0.0;
  int kmin = std::max(0, std::max(j2-j3-m1, j1-j3+m2));
  int kmax = std::min(j1+j2-j3, std::min(j1-m1, j2+m2));
  for (int k=kmin;k<=kmax;++k){
    double d = factd(k)*factd(j1+j2-j3-k)*factd(j1-m1-k)*factd(j2+m2-k)
             * factd(j3-j2+m1+k)*factd(j3-j1-m2+k);
    s += ((k&1)? -1.0 : 1.0)/d;
  }
  return c*s;
}

static void qmat(int l, std::complex<double>* q){
  int d = 2*l+1;
  for (int a=0;a<d*d;++a) q[a] = std::complex<double>(0.0,0.0);
  const double r2 = 1.0/std::sqrt(2.0);
  for (int m=-l; m<0; ++m){
    q[(l+m)*d + (l-m)] = std::complex<double>(r2, 0.0);
    q[(l+m)*d + (l+m)] = std::complex<double>(0.0, -r2);
  }
  q[l*d + l] = std::complex<double>(1.0,0.0);
  for (int m=1; m<=l; ++m){
    double sg = (m&1)? -1.0 : 1.0;
    q[(l+m)*d + (l+m)] = std::complex<double>(sg*r2, 0.0);
    q[(l+m)*d + (l-m)] = std::complex<double>(0.0, sg*r2);
  }
  std::complex<double> ph = (l==0)? std::complex<double>(1,0)
                        : (l==1)? std::complex<double>(0,-1)
                                : std::complex<double>(-1,0);   // (-i)^l
  for (int a=0;a<d*d;++a) q[a] *= ph;
}

static void compute_cg(float* outv){
  const int npaths_to[3] = {3,6,6};
  for (int p=0;p<NPATH;++p){
    int l1=PL1[p], l2=PL2[p], l3=PL3[p];
    int d1=2*l1+1, d2=2*l2+1, d3=2*l3+1;
    std::complex<double> C[5][5][5];
    for (int a=0;a<5;++a) for(int b=0;b<5;++b) for(int c=0;c<5;++c) C[a][b][c]=std::complex<double>(0,0);
    for (int m1=-l1;m1<=l1;++m1) for (int m2=-l2;m2<=l2;++m2){
      int m3=m1+m2;
      if (std::abs(m3)<=l3) C[l1+m1][l2+m2][l3+m3] = su2_cg(l1,m1,l2,m2,l3,m3);
    }
    std::complex<double> U1[25],U2[25],U3[25];
    qmat(l1,U1); qmat(l2,U2); qmat(l3,U3);
    double Cr[5][5][5]; double nrm=0.0;
    for (int a=0;a<d1;++a) for (int b=0;b<d2;++b) for (int c=0;c<d3;++c){
      std::complex<double> s(0,0);
      for (int i=0;i<d1;++i) for (int j=0;j<d2;++j) for (int k=0;k<d3;++k)
        s += U1[i*d1+a]*U2[j*d2+b]*std::conj(U3[k*d3+c])*C[i][j][k];
      Cr[a][b][c] = s.real();
      nrm += s.real()*s.real();
    }
    nrm = std::sqrt(nrm);
    double alpha = 1.0/std::sqrt(64.0*(double)npaths_to[l3]);
    float* o = outv + CGOFF[p];
    int idx=0;
    for (int a=0;a<d1;++a) for (int b=0;b<d2;++b) for (int c=0;c<d3;++c)
      o[idx++] = (float)(Cr[a][b][c]/nrm*alpha);
  }
}

// ---------------- device ----------------
typedef short bf16x8 __attribute__((ext_vector_type(8)));
typedef float f32x4 __attribute__((ext_vector_type(4)));

#define MFMA16(A,B,C) __builtin_amdgcn_mfma_f32_16x16x32_bf16((A),(B),(C),0,0,0)

__device__ __forceinline__ unsigned cvtpk_bf16(float a, float b){
  unsigned r;
  asm("v_cvt_pk_bf16_f32 %0, %1, %2" : "=v"(r) : "v"(a), "v"(b));
  return r;
}

// x-fragment: lane (cl,q) holds x[row=cl][u=kt*32+q*8 ..+7]; XOR-swizzled 16B chunks (R2-verified)
__device__ __forceinline__ bf16x8 afrag(const unsigned short* s_xt, int plane, int kt, int row, int q){
  int c = (kt*4 + q) ^ (row & 7);
  return *reinterpret_cast<const bf16x8*>(s_xt + (plane*16 + row)*64 + c*8);
}
// W-fragment: lane (cl,q) holds W^T[w=wt*16+cl][u=kt*32+q*8..+7]
__device__ __forceinline__ bf16x8 wfrag(const unsigned short* WT, int p, int wt, int cl, int kt, int q){
  return *reinterpret_cast<const bf16x8*>(WT + p*4096 + (wt*16+cl)*64 + kt*32 + q*8);
}
__device__ __forceinline__ void xt_write_pk(unsigned short* s_xt, int plane, int n, int t16, uint2 pk){
  const int swz = (((t16>>1)^(n&7))<<3) + ((t16&1)<<2);
  *reinterpret_cast<uint2*>(s_xt + (plane*16 + n)*64 + swz) = pk;
}

__device__ __forceinline__ void pack_x(const float4& r0, const float4* r1, const float4* r2, uint2* xpk){
  const float* f0 = reinterpret_cast<const float*>(&r0);
  const float* f1 = reinterpret_cast<const float*>(r1);
  const float* f2 = reinterpret_cast<const float*>(r2);
  xpk[0].x = cvtpk_bf16(f0[0], f0[1]);  xpk[0].y = cvtpk_bf16(f0[2], f0[3]);
  #pragma unroll
  for (int i=0;i<3;++i){
    xpk[1+i].x = cvtpk_bf16(f1[0*3+i], f1[1*3+i]);
    xpk[1+i].y = cvtpk_bf16(f1[2*3+i], f1[3*3+i]);
  }
  #pragma unroll
  for (int i=0;i<5;++i){
    xpk[4+i].x = cvtpk_bf16(f2[0*5+i], f2[1*5+i]);
    xpk[4+i].y = cvtpk_bf16(f2[2*5+i], f2[3*5+i]);
  }
}

// stage one tile (x rows + yc) — HALF-templated compacted yc
template<int HALF>
__device__ __forceinline__ void stage_tile(const float* __restrict__ x, const float* __restrict__ y,
                                           int nbase, unsigned short* s_xt, float* s_yg,
                                           const CGArg& cga, int tid, int n_s, int t16){
  const float* xb = x + (size_t)(nbase + n_s)*576;
  float4 r0 = *reinterpret_cast<const float4*>(xb + t16*4);
  float4 r1[3], r2[5];
  #pragma unroll
  for (int i=0;i<3;++i) r1[i] = *reinterpret_cast<const float4*>(xb + 64 + t16*12 + 4*i);
  #pragma unroll
  for (int i=0;i<5;++i) r2[i] = *reinterpret_cast<const float4*>(xb + 256 + t16*20 + 4*i);

  float yl[9];
  {
    const float* yrow = y + (size_t)(nbase + t16)*9;
    #pragma unroll
    for (int j=0;j<9;++j) yl[j] = yrow[j];
  }

  uint2 xpk[9];
  pack_x(r0, r1, r2, xpk);
  #pragma unroll
  for (int pl=0; pl<9; ++pl) xt_write_pk(s_xt, pl, n_s, t16, xpk[pl]);

  constexpr int RB = (HALF==0)? 48 : 80;
  if (tid < 16){
    #pragma unroll
    for (int j=0;j<9;++j) s_yg[(RB+j)*16 + tid] = yl[j];
  }

  if constexpr (HALF==0){
    constexpr int GPp[4] = {5,7,10,13};
    constexpr int NB[4]  = {0,9,18,33};
    #pragma unroll
    for (int u=0; u<4; ++u){
      const int p = GPp[u];
      const int d2=2*PL2[p]+1, d3=2*PL3[p]+1;
      const int cnt = (2*PL1[p]+1)*d3*16;
      for (int idx=tid; idx<cnt; idx+=256){
        int ik = idx >> 4;
        int i  = ik/d3;
        int k  = ik - i*d3;
        float s=0.f;
        for (int j=0;j<d2;++j)
          s += yl[YOFF[PL2[p]]+j]*cga.v[CGOFF[p]+(i*d2+j)*d3+k];
        s_yg[(NB[u]+ik)*16 + t16] = s;
      }
    }
  } else {
    constexpr int GPp[4] = {6,8,11,14};
    constexpr int NB[4]  = {0,15,30,55};
    #pragma unroll
    for (int u=0; u<4; ++u){
      const int p = GPp[u];
      const int d2=2*PL2[p]+1, d3=2*PL3[p]+1;
      const int cnt = (2*PL1[p]+1)*d3*16;
      for (int idx=tid; idx<cnt; idx+=256){
        int ik = idx >> 4;
        int i  = ik/d3;
        int k  = ik - i*d3;
        float s=0.f;
        for (int j=0;j<d2;++j)
          s += yl[YOFF[PL2[p]]+j]*cga.v[CGOFF[p]+(i*d2+j)*d3+k];
        s_yg[(NB[u]+ik)*16 + t16] = s;
      }
    }
  }
}

// ---- doubled (2-tile) flipped path bodies: T rows w=q*4+r, cols n=cl ----
template<int PB,int D1,int D3,int E0,int AB>
__device__ __forceinline__ void gen2(const unsigned short* xt0, const unsigned short* xt1,
                                     bf16x8 b0, bf16x8 b1,
                                     const float* yg0, const float* yg1,
                                     f32x4* a0, f32x4* a1, int cl, int q){
  const f32x4 z4 = {0.f,0.f,0.f,0.f};
  #pragma unroll
  for (int i=0;i<D1;++i){
    f32x4 T0 = MFMA16(b0, afrag(xt0,PB+i,0,cl,q), z4);
    T0       = MFMA16(b1, afrag(xt0,PB+i,1,cl,q), T0);
    f32x4 T1 = MFMA16(b0, afrag(xt1,PB+i,0,cl,q), z4);
    T1       = MFMA16(b1, afrag(xt1,PB+i,1,cl,q), T1);
    #pragma unroll
    for (int k=0;k<D3;++k){
      a0[AB+k] += T0*yg0[(E0+i*D3+k)*16];
      a1[AB+k] += T1*yg1[(E0+i*D3+k)*16];
    }
  }
}
template<int PB,int D1,int AB>   // (l,0,l): acc[AB+i] += cy*T_i
__device__ __forceinline__ void dl0_2(const unsigned short* xt0, const unsigned short* xt1,
                                      bf16x8 b0, bf16x8 b1, float cy0, float cy1,
                                      f32x4* a0, f32x4* a1, int cl, int q){
  const f32x4 z4 = {0.f,0.f,0.f,0.f};
  #pragma unroll
  for (int i=0;i<D1;++i){
    f32x4 T0 = MFMA16(b0, afrag(xt0,PB+i,0,cl,q), z4);
    T0       = MFMA16(b1, afrag(xt0,PB+i,1,cl,q), T0);
    f32x4 T1 = MFMA16(b0, afrag(xt1,PB+i,0,cl,q), z4);
    T1       = MFMA16(b1, afrag(xt1,PB+i,1,cl,q), T1);
    a0[AB+i] += T0*cy0;
    a1[AB+i] += T1*cy1;
  }
}
template<int D3,int YE,int AB>  // (0,l,l): plane-0; acc[AB+k] += c*y[YE+k]*T
__device__ __forceinline__ void d0l_2(const unsigned short* xt0, const unsigned short* xt1,
                                      bf16x8 b0, bf16x8 b1, float c,
                                      const float* yg0, const float* yg1,
                                      f32x4* a0, f32x4* a1, int cl, int q){
  const f32x4 z4 = {0.f,0.f,0.f,0.f};
  f32x4 T0 = MFMA16(b0, afrag(xt0,0,0,cl,q), z4);
  T0       = MFMA16(b1, afrag(xt0,0,1,cl,q), T0);
  f32x4 T1 = MFMA16(b0, afrag(xt1,0,0,cl,q), z4);
  T1       = MFMA16(b1, afrag(xt1,0,1,cl,q), T1);
  #pragma unroll
  for (int k=0;k<D3;++k){
    a0[AB+k] += T0*(c*yg0[(YE+k)*16]);
    a1[AB+k] += T1*(c*yg1[(YE+k)*16]);
  }
}
template<int PB,int D1,int YE>  // (l,l,0): acc[0] += c * sum_i y[YE+i]*T_i
__device__ __forceinline__ void dll0_2(const unsigned short* xt0, const unsigned short* xt1,
                                       bf16x8 b0, bf16x8 b1, float c,
                                       const float* yg0, const float* yg1,
                                       f32x4* a0, f32x4* a1, int cl, int q){
  const f32x4 z4 = {0.f,0.f,0.f,0.f};
  f32x4 s0 = z4, s1 = z4;
  #pragma unroll
  for (int i=0;i<D1;++i){
    f32x4 T0 = MFMA16(b0, afrag(xt0,PB+i,0,cl,q), z4);
    T0       = MFMA16(b1, afrag(xt0,PB+i,1,cl,q), T0);
    f32x4 T1 = MFMA16(b0, afrag(xt1,PB+i,0,cl,q), z4);
    T1       = MFMA16(b1, afrag(xt1,PB+i,1,cl,q), T1);
    s0 += T0*yg0[(YE+i)*16];
    s1 += T1*yg1[(YE+i)*16];
  }
  a0[0] += s0*c;
  a1[0] += s1*c;
}

__global__ __launch_bounds__(256, 3)
void tp_kernel(const float* __restrict__ x, const float* __restrict__ y,
               const unsigned short* __restrict__ WT, float* __restrict__ out, CGArg cga)
{
  __shared__ __align__(16) unsigned short s_xt0[9*16*64];  // 18432 B
  __shared__ __align__(16) unsigned short s_xt1[9*16*64];  // 18432 B
  __shared__ __align__(16) float s_yg0[YGMAX*16];          // 5696 B
  __shared__ __align__(16) float s_yg1[YGMAX*16];          // 5696 B

  const int bid = blockIdx.x;
  // XCD-pairing: both halves of a pair share bid%8 -> same XCD
  const int pair = (bid & 7) | ((bid >> 4) << 3);   // 0..1023
  const int half = (bid >> 3) & 1;
  const int n0 = pair * 32;

  const int tid = threadIdx.x;
  const int n_s = tid>>4, t16 = tid&15;

  if (half == 0){
    stage_tile<0>(x, y, n0,    s_xt0, s_yg0, cga, tid, n_s, t16);
    stage_tile<0>(x, y, n0+16, s_xt1, s_yg1, cga, tid, n_s, t16);
  } else {
    stage_tile<1>(x, y, n0,    s_xt0, s_yg0, cga, tid, n_s, t16);
    stage_tile<1>(x, y, n0+16, s_xt1, s_yg1, cga, tid, n_s, t16);
  }
  __syncthreads();

  const int lane = tid & 63, wt = tid >> 6;
  const int cl = lane & 15, q = lane >> 4;
  const float* yg0 = s_yg0 + cl;
  const float* yg1 = s_yg1 + cl;
  const int wbase = wt*16 + q*4;

  const f32x4 z4 = {0.f,0.f,0.f,0.f};
  bf16x8 b0,b1,nb0,nb1;

  #define LDB(P) { nb0 = wfrag(WT,P,wt,cl,0,q); nb1 = wfrag(WT,P,wt,cl,1,q); }
  #define ADV    { b0 = nb0; b1 = nb1; }

  if (half == 0){
    constexpr int RB = 48;
    const float y00 = yg0[RB*16], y01 = yg1[RB*16];
    f32x4 a0[4] = {z4,z4,z4,z4};
    f32x4 a1[4] = {z4,z4,z4,z4};
    b0 = wfrag(WT,0,wt,cl,0,q); b1 = wfrag(WT,0,wt,cl,1,q);

    LDB(1);  dl0_2<0,1,0>(s_xt0,s_xt1, b0,b1, cga.v[CGOFF[0]]*y00, cga.v[CGOFF[0]]*y01, a0,a1, cl,q); ADV; // p0
    LDB(3);  d0l_2<3,RB+1,1>(s_xt0,s_xt1, b0,b1, cga.v[CGOFF[1]], yg0,yg1, a0,a1, cl,q);              ADV; // p1
    LDB(4);  dl0_2<1,3,1>(s_xt0,s_xt1, b0,b1, cga.v[CGOFF[3]]*y00, cga.v[CGOFF[3]]*y01, a0,a1, cl,q); ADV; // p3
    LDB(5);  dll0_2<1,3,RB+1>(s_xt0,s_xt1, b0,b1, cga.v[CGOFF[4]], yg0,yg1, a0,a1, cl,q);             ADV; // p4
    LDB(7);  gen2<1,3,3,0,1>(s_xt0,s_xt1, b0,b1, yg0,yg1, a0,a1, cl,q);                               ADV; // p5
    LDB(10); gen2<1,3,3,9,1>(s_xt0,s_xt1, b0,b1, yg0,yg1, a0,a1, cl,q);                               ADV; // p7
    LDB(12); gen2<4,5,3,18,1>(s_xt0,s_xt1, b0,b1, yg0,yg1, a0,a1, cl,q);                              ADV; // p10
    LDB(13); dll0_2<4,5,RB+4>(s_xt0,s_xt1, b0,b1, cga.v[CGOFF[12]], yg0,yg1, a0,a1, cl,q);            ADV; // p12
             gen2<4,5,3,33,1>(s_xt0,s_xt1, b0,b1, yg0,yg1, a0,a1, cl,q);                                   // p13

    #pragma unroll
    for (int tt=0; tt<2; ++tt){
      const f32x4* a = (tt==0)? a0 : a1;
      float* orow = out + (size_t)(n0 + tt*16 + cl)*576;
      *reinterpret_cast<float4*>(orow + wbase) =
          make_float4(a[0][0],a[0][1],a[0][2],a[0][3]);
      float4 v0 = make_float4(a[1][0],a[2][0],a[3][0],a[1][1]);
      float4 v1 = make_float4(a[2][1],a[3][1],a[1][2],a[2][2]);
      float4 v2 = make_float4(a[3][2],a[1][3],a[2][3],a[3][3]);
      float4* qp = reinterpret_cast<float4*>(orow + 64 + wbase*3);
      qp[0]=v0; qp[1]=v1; qp[2]=v2;
    }
  } else {
    constexpr int RB = 80;
    const float y00 = yg0[RB*16], y01 = yg1[RB*16];
    f32x4 a0[5] = {z4,z4,z4,z4,z4};
    f32x4 a1[5] = {z4,z4,z4,z4,z4};
    b0 = wfrag(WT,2,wt,cl,0,q); b1 = wfrag(WT,2,wt,cl,1,q);

    LDB(6);  d0l_2<5,RB+4,0>(s_xt0,s_xt1, b0,b1, cga.v[CGOFF[2]], yg0,yg1, a0,a1, cl,q);              ADV; // p2
    LDB(8);  gen2<1,3,5,0,0>(s_xt0,s_xt1, b0,b1, yg0,yg1, a0,a1, cl,q);                               ADV; // p6
    LDB(9);  gen2<1,3,5,15,0>(s_xt0,s_xt1, b0,b1, yg0,yg1, a0,a1, cl,q);                              ADV; // p8
    LDB(11); dl0_2<4,5,0>(s_xt0,s_xt1, b0,b1, cga.v[CGOFF[9]]*y00, cga.v[CGOFF[9]]*y01, a0,a1, cl,q); ADV; // p9
    LDB(14); gen2<4,5,5,30,0>(s_xt0,s_xt1, b0,b1, yg0,yg1, a0,a1, cl,q);                              ADV; // p11
             gen2<4,5,5,55,0>(s_xt0,s_xt1, b0,b1, yg0,yg1, a0,a1, cl,q);                                   // p14

    #pragma unroll
    for (int tt=0; tt<2; ++tt){
      const f32x4* a = (tt==0)? a0 : a1;
      float* orow = out + (size_t)(n0 + tt*16 + cl)*576;
      float4 v0 = make_float4(a[0][0],a[1][0],a[2][0],a[3][0]);
      float4 v1 = make_float4(a[4][0],a[0][1],a[1][1],a[2][1]);
      float4 v2 = make_float4(a[3][1],a[4][1],a[0][2],a[1][2]);
      float4 v3 = make_float4(a[2][2],a[3][2],a[4][2],a[0][3]);
      float4 v4 = make_float4(a[1][3],a[2][3],a[3][3],a[4][3]);
      float4* qp = reinterpret_cast<float4*>(orow + 256 + wbase*5);
      qp[0]=v0; qp[1]=v1; qp[2]=v2; qp[3]=v3; qp[4]=v4;
    }
  }
  #undef LDB
  #undef ADV
}

// W[p][u][w] (fp32) -> WT[p][w][u] (bf16, RNE) once per launch
__global__ void wt_kernel(const float* __restrict__ W, unsigned short* __restrict__ WT){
  int t = blockIdx.x*256 + threadIdx.x;      // 61440 total
  int p = t >> 12, r = t & 4095, w = r >> 6, u = r & 63;
  float f = W[(p<<12) + (u<<6) + w];
  unsigned fu = __builtin_bit_cast(unsigned, f);
  unsigned rr = (fu + 0x7FFFu + ((fu>>16)&1u)) >> 16;
  WT[t] = (unsigned short)rr;
}

// ---------------- launch ----------------
extern "C" void kernel_launch(void* const* d_in, const int* in_sizes, int n_in,
                              void* d_out, int out_size, void* d_ws, size_t ws_size,
                              hipStream_t stream) {
  const float* x = (const float*)d_in[0];
  const float* y = (const float*)d_in[1];
  const float* W = (const float*)d_in[2];
  float* out = (float*)d_out;
  (void)in_sizes; (void)n_in; (void)out_size; (void)ws_size;

  unsigned short* WT = (unsigned short*)d_ws;   // 61440 * 2 B

  CGArg cga;
  compute_cg(cga.v);

  hipLaunchKernelGGL(wt_kernel, dim3(240), dim3(256), 0, stream, W, WT);
  hipLaunchKernelGGL(tp_kernel, dim3(2048), dim3(256), 0, stream, x, y, WT, out, cga);
}